// Round 7
// baseline (592.568 us; speedup 1.0000x reference)
//
#include <hip/hip_runtime.h>
#include <hip/hip_bf16.h>
#include <cstdint>
#include <cstddef>

// ---------- types ----------
typedef __bf16 bf16x8 __attribute__((ext_vector_type(8)));
typedef float  f32x4  __attribute__((ext_vector_type(4)));

#define VOC    50000
#define W2     4224      // unified K: 4096 (kron) + 128 (concat)
#define NSTAGE 33        // 33 stages x 128 k
#define STG    8192      // elems per stage (128 k x 64 n) = 16 KB
#define XSTR   72        // LDS row stride in bf16 elems (144 B)

// ---------- static device scratch ----------
__device__ __attribute__((aligned(256))) unsigned short g_vocT[(size_t)VOC * 64];
__device__ __attribute__((aligned(256))) unsigned short g_X1[(size_t)65536 * 64];  // L0 outputs
__device__ __attribute__((aligned(256))) unsigned short g_roots[2048 * 64];
// weights in stage-fragment order: d = s*8192 + kbl*2048 + q*512 + n*8 + z
// = W[n][k], k = s*128 + kbl*32 + q*8 + z   (s=32 holds the concat weights)
__device__ __attribute__((aligned(256))) unsigned short g_cpstU[64 * W2];
__device__ __attribute__((aligned(256))) unsigned short g_cprtU[64 * W2];
__device__ float g_smw[7 * 64];
__device__ float g_smb[7];
__device__ float g_biasC[64];   // cps_b + cpst_b
__device__ float g_biasF[64];   // cpr_b + cprt_b

__device__ __forceinline__ float b2f(unsigned short u) {
    unsigned int x = ((unsigned int)u) << 16;
    return __builtin_bit_cast(float, x);
}
__device__ __forceinline__ unsigned short f2b(float f) {
    return __builtin_bit_cast(unsigned short, (__bf16)f);
}
__device__ __forceinline__ float scrub(float v) {
    return fminf(fmaxf(v, -64.f), 64.f);
}
__device__ __forceinline__ float ldf(const void* p, size_t i, int isb) {
    return isb ? b2f(((const unsigned short*)p)[i]) : ((const float*)p)[i];
}
__device__ __forceinline__ int detect_isb(const void* voc_b) {
    const unsigned int* p = (const unsigned int*)voc_b;
    int ok = 1;
    for (int k = 0; k < 32; k++) {
        float v = b2f((unsigned short)(p[k] & 0xFFFFu));
        if (!(fabsf(v) <= 0.0502f)) ok = 0;
    }
    return ok;
}

// ---------- kernel: reorder weights into stage-fragment order (coalesced) ----------
// grid = 33 (one stage per WG)
__global__ __launch_bounds__(256) void k_reorder(
    const void* voc_b,
    const void* cps_w, const void* cps_b, const void* cpst_w, const void* cpst_b,
    const void* cpr_w, const void* cpr_b, const void* cprt_w, const void* cprt_b,
    const void* sm_w, const void* sm_b)
{
    __shared__ unsigned short tileA[64][132];
    __shared__ unsigned short tileB[64][132];
    const int isb = detect_isb(voc_b);
    const int s = blockIdx.x;          // 0..32
    const int tid = threadIdx.x;
    for (int j = 0; j < 32; j++) {     // read W[n][s*128 + kk], coalesced along kk
        int lin = j * 256 + tid;
        int n = lin >> 7, kk = lin & 127;
        float v1 = (s < 32) ? ldf(cpst_w, (size_t)n * 4096 + s * 128 + kk, isb)
                            : ldf(cps_w,  (size_t)n * 128 + kk, isb);
        float v2 = (s < 32) ? ldf(cprt_w, (size_t)n * 4096 + s * 128 + kk, isb)
                            : ldf(cpr_w,  (size_t)n * 128 + kk, isb);
        tileA[n][kk] = f2b(v1);
        tileB[n][kk] = f2b(v2);
    }
    __syncthreads();
    for (int j = 0; j < 32; j++) {     // write fragment order, coalesced along d
        int lin = j * 256 + tid;
        int kbl = lin >> 11, rem = lin & 2047;
        int q = rem >> 9, rem2 = rem & 511;
        int n = rem2 >> 3, z = rem2 & 7;
        int kk = kbl * 32 + q * 8 + z;
        g_cpstU[(size_t)s * STG + lin] = tileA[n][kk];
        g_cprtU[(size_t)s * STG + lin] = tileB[n][kk];
    }
    if (s == 0) {
        for (int i = tid; i < 448; i += 256) g_smw[i] = ldf(sm_w, i, isb);
        if (tid < 64) {
            g_biasC[tid] = ldf(cps_b, tid, isb) + ldf(cpst_b, tid, isb);
            g_biasF[tid] = ldf(cpr_b, tid, isb) + ldf(cprt_b, tid, isb);
        }
        if (tid < 7) g_smb[tid] = ldf(sm_b, tid, isb);
    }
}

// ---------- kernel: voc_w (64 x 50000) -> g_vocT[50000][64] bf16, fold voc_b ----------
__global__ __launch_bounds__(256) void k_vocT(const void* __restrict__ voc_w,
                                              const void* __restrict__ voc_b) {
    __shared__ float tile[64][65];
    __shared__ float vb[64];
    const int isb = detect_isb(voc_b);
    int t = threadIdx.x;
    if (t < 64) vb[t] = ldf(voc_b, t, isb);
    int v0 = blockIdx.x * 64;
    int vl = t & 63, dr = t >> 6;
    #pragma unroll
    for (int i = 0; i < 16; i++) {
        int d = dr * 16 + i;
        int v = v0 + vl;
        tile[vl][d] = (v < VOC) ? ldf(voc_w, (size_t)d * VOC + v, isb) : 0.f;
    }
    __syncthreads();
    int dl = t & 63, vr0 = t >> 6;
    #pragma unroll
    for (int i = 0; i < 16; i++) {
        int vr = vr0 * 16 + i;
        int v = v0 + vr;
        if (v < VOC) g_vocT[(size_t)v * 64 + dl] = f2b(tile[vr][dl] + vb[dl]);
    }
}

// ---------- kernel: level 0 (leaves -> 32 nodes/tree), 8 trees/WG, W=4, C=4 ----------
__global__ __launch_bounds__(256, 1) void k_L0(const int* __restrict__ lleaf,
                                               const int* __restrict__ rleaf)
{
    __shared__ __attribute__((aligned(16))) unsigned short Xs[512 * XSTR];  // 73728 B
    __shared__ __attribute__((aligned(16))) unsigned short Bs[2][STG];      // 32 KB
    __shared__ float biasC[64];
    const int tid = threadIdx.x;
    const int wg  = blockIdx.x;
    if (tid < 64) biasC[tid] = g_biasC[tid];

    // ---- leaf gather: slot = t*64 + leaf_i ----
    #pragma unroll
    for (int it = 0; it < 2; it++) {
        int row = it * 256 + tid;                // 0..511
        int t = row >> 6, i = row & 63;
        int g = wg * 8 + t;                      // 0..1023 left, 1024..2047 right
        int b = (g < 1024) ? g : g - 1024;
        const int* lv = (g < 1024) ? lleaf : rleaf;
        int idx = lv[b * 64 + i];
        idx = (idx < 0) ? 0 : ((idx >= VOC) ? VOC - 1 : idx);
        const uint4* src = (const uint4*)(g_vocT + (size_t)idx * 64);
        uint4* dst = (uint4*)(Xs + row * XSTR);
        #pragma unroll
        for (int z = 0; z < 8; z++) dst[z] = src[z];
    }

    // prefetch stage 0 (64 B/thread)
    uint4 r[4];
    #pragma unroll
    for (int j = 0; j < 4; j++)
        r[j] = *(const uint4*)(g_cpstU + j * 2048 + (size_t)tid * 8);

    __syncthreads();

    const int lane = tid & 63, wave = tid >> 6;
    const int q = lane >> 4, sub = lane & 15;

    int slotL[4];
    float Lf[4][2][8];
    #pragma unroll
    for (int c = 0; c < 4; c++) {
        int m = (wave * 4 + c) * 16 + sub;       // 0..255
        int t = m >> 5, n = m & 31;
        slotL[c] = (t * 64 + 2 * n) * XSTR;
        bf16x8 o0 = *(const bf16x8*)(Xs + slotL[c] + q * 8);
        bf16x8 o1 = *(const bf16x8*)(Xs + slotL[c] + 32 + q * 8);
        #pragma unroll
        for (int z = 0; z < 8; z++) { Lf[c][0][z] = (float)o0[z]; Lf[c][1][z] = (float)o1[z]; }
    }

    f32x4 acc[4][4];
    #pragma unroll
    for (int c = 0; c < 4; c++)
        #pragma unroll
        for (int nt = 0; nt < 4; nt++)
            #pragma unroll
            for (int z = 0; z < 4; z++) acc[c][nt][z] = 0.f;

    for (int s = 0; s < NSTAGE; s++) {
        const int par = s & 1;
        #pragma unroll
        for (int j = 0; j < 4; j++)
            *(uint4*)(Bs[par] + j * 2048 + tid * 8) = r[j];
        __syncthreads();
        if (s < NSTAGE - 1) {
            const unsigned short* base = g_cpstU + (size_t)(s + 1) * STG;
            #pragma unroll
            for (int j = 0; j < 4; j++)
                r[j] = *(const uint4*)(base + j * 2048 + (size_t)tid * 8);
        }
        const unsigned short* Bp = Bs[par];
        if (s < 32) {                            // kron
            float Li[4][2];
            #pragma unroll
            for (int c = 0; c < 4; c++) {
                unsigned int lp = *(const unsigned int*)(Xs + slotL[c] + 2 * s);
                Li[c][0] = b2f((unsigned short)(lp & 0xFFFFu));
                Li[c][1] = b2f((unsigned short)(lp >> 16));
            }
            #pragma unroll
            for (int ii = 0; ii < 2; ii++)
                #pragma unroll
                for (int p2 = 0; p2 < 2; p2++) {
                    int kbl = 2 * ii + p2;
                    bf16x8 bfr[4];
                    #pragma unroll
                    for (int nt = 0; nt < 4; nt++)
                        bfr[nt] = *(const bf16x8*)(Bp + kbl * 2048 + q * 512 + (nt * 16 + sub) * 8);
                    #pragma unroll
                    for (int c = 0; c < 4; c++) {
                        bf16x8 afr;
                        #pragma unroll
                        for (int z = 0; z < 8; z++) afr[z] = (__bf16)(Lf[c][p2][z] * Li[c][ii]);
                        #pragma unroll
                        for (int nt = 0; nt < 4; nt++)
                            acc[c][nt] = __builtin_amdgcn_mfma_f32_16x16x32_bf16(afr, bfr[nt], acc[c][nt], 0, 0, 0);
                    }
                }
        } else {                                 // concat(L,R)
            bf16x8 A4[4][4];
            #pragma unroll
            for (int c = 0; c < 4; c++) {
                A4[c][0] = *(const bf16x8*)(Xs + slotL[c] + q * 8);
                A4[c][1] = *(const bf16x8*)(Xs + slotL[c] + 32 + q * 8);
                A4[c][2] = *(const bf16x8*)(Xs + slotL[c] + XSTR + q * 8);
                A4[c][3] = *(const bf16x8*)(Xs + slotL[c] + XSTR + 32 + q * 8);
            }
            #pragma unroll
            for (int kbl = 0; kbl < 4; kbl++) {
                bf16x8 bfr[4];
                #pragma unroll
                for (int nt = 0; nt < 4; nt++)
                    bfr[nt] = *(const bf16x8*)(Bp + kbl * 2048 + q * 512 + (nt * 16 + sub) * 8);
                #pragma unroll
                for (int c = 0; c < 4; c++)
                    #pragma unroll
                    for (int nt = 0; nt < 4; nt++)
                        acc[c][nt] = __builtin_amdgcn_mfma_f32_16x16x32_bf16(A4[c][kbl], bfr[nt], acc[c][nt], 0, 0, 0);
            }
        }
        __syncthreads();
    }

    // epilogue -> g_X1
    #pragma unroll
    for (int c = 0; c < 4; c++)
        #pragma unroll
        for (int nt = 0; nt < 4; nt++) {
            int e = nt * 16 + sub;
            #pragma unroll
            for (int rr = 0; rr < 4; rr++) {
                int m = (wave * 4 + c) * 16 + q * 4 + rr;
                g_X1[((size_t)wg * 256 + m) * 64 + e] = f2b(tanhf(scrub(acc[c][nt][rr] + biasC[e])));
            }
        }
}

// ---------- kernel: levels 1..5 fused, 8 trees/WG (32-slot trees), W=2 ----------
__global__ __launch_bounds__(128, 1) void k_tree()
{
    __shared__ __attribute__((aligned(16))) unsigned short Xs[256 * XSTR];  // 36864 B
    __shared__ __attribute__((aligned(16))) unsigned short Bs[2][STG];      // 32 KB
    __shared__ float biasC[64];
    const int tid = threadIdx.x;                 // 0..127
    const int wg  = blockIdx.x;
    if (tid < 64) biasC[tid] = g_biasC[tid];

    // stage 256 L0-output rows
    #pragma unroll
    for (int it = 0; it < 4; it++) {
        int task = it * 128 + tid;               // 0..511
        int row = task >> 1, half = task & 1;
        const uint4* src = (const uint4*)(g_X1 + ((size_t)wg * 256 + row) * 64 + half * 32);
        uint4* dst = (uint4*)(Xs + row * XSTR + half * 32);
        #pragma unroll
        for (int z = 0; z < 4; z++) dst[z] = src[z];
    }

    // prefetch stage 0 (128 B/thread)
    uint4 r[8];
    #pragma unroll
    for (int j = 0; j < 8; j++)
        r[j] = *(const uint4*)(g_cpstU + j * 1024 + (size_t)tid * 8);

    __syncthreads();

    const int lane = tid & 63, wave = tid >> 6;  // wave 0..1
    const int q = lane >> 4, sub = lane & 15;

    int sg = 0;                                  // continuous stage counter (parity)
    for (int lidx = 0; lidx < 5; lidx++) {
        const int lg = 4 - lidx;
        const int cnew = 1 << lg;
        const int nodes = 8 << lg;               // 128,64,32,16,8
        const int nchunks = (nodes + 15) >> 4;   // 8,4,2,1,1
        const int chpw = (nchunks >= 2) ? (nchunks >> 1) : 1;  // 4,2,1,1,1

        int act[4], slotL[4];
        float Lf[4][2][8];
        #pragma unroll
        for (int c = 0; c < 4; c++) {
            int ch = wave * chpw + c;
            act[c] = (c < chpw) && (ch < nchunks);
            int m = ch * 16 + sub;
            if (m >= nodes) m = 0;
            int t = m >> lg, n = m & (cnew - 1);
            slotL[c] = (t * 32 + 2 * n) * XSTR;
            if (act[c]) {
                bf16x8 o0 = *(const bf16x8*)(Xs + slotL[c] + q * 8);
                bf16x8 o1 = *(const bf16x8*)(Xs + slotL[c] + 32 + q * 8);
                #pragma unroll
                for (int z = 0; z < 8; z++) { Lf[c][0][z] = (float)o0[z]; Lf[c][1][z] = (float)o1[z]; }
            }
        }

        f32x4 acc[4][4];
        #pragma unroll
        for (int c = 0; c < 4; c++)
            #pragma unroll
            for (int nt = 0; nt < 4; nt++)
                #pragma unroll
                for (int z = 0; z < 4; z++) acc[c][nt][z] = 0.f;

        for (int s = 0; s < NSTAGE; s++) {
            const int par = sg & 1;
            #pragma unroll
            for (int j = 0; j < 8; j++)
                *(uint4*)(Bs[par] + j * 1024 + tid * 8) = r[j];
            __syncthreads();
            {   // prefetch next stage (wraps at level boundary: same weights)
                int sn = (s == NSTAGE - 1) ? 0 : s + 1;
                const unsigned short* base = g_cpstU + (size_t)sn * STG;
                #pragma unroll
                for (int j = 0; j < 8; j++)
                    r[j] = *(const uint4*)(base + j * 1024 + (size_t)tid * 8);
            }
            const unsigned short* Bp = Bs[par];
            if (s < 32) {                        // kron
                float Li[4][2];
                #pragma unroll
                for (int c = 0; c < 4; c++) {
                    if (!act[c]) continue;
                    unsigned int lp = *(const unsigned int*)(Xs + slotL[c] + 2 * s);
                    Li[c][0] = b2f((unsigned short)(lp & 0xFFFFu));
                    Li[c][1] = b2f((unsigned short)(lp >> 16));
                }
                #pragma unroll
                for (int ii = 0; ii < 2; ii++)
                    #pragma unroll
                    for (int p2 = 0; p2 < 2; p2++) {
                        int kbl = 2 * ii + p2;
                        bf16x8 bfr[4];
                        #pragma unroll
                        for (int nt = 0; nt < 4; nt++)
                            bfr[nt] = *(const bf16x8*)(Bp + kbl * 2048 + q * 512 + (nt * 16 + sub) * 8);
                        #pragma unroll
                        for (int c = 0; c < 4; c++) {
                            if (!act[c]) continue;
                            bf16x8 afr;
                            #pragma unroll
                            for (int z = 0; z < 8; z++) afr[z] = (__bf16)(Lf[c][p2][z] * Li[c][ii]);
                            #pragma unroll
                            for (int nt = 0; nt < 4; nt++)
                                acc[c][nt] = __builtin_amdgcn_mfma_f32_16x16x32_bf16(afr, bfr[nt], acc[c][nt], 0, 0, 0);
                        }
                    }
            } else {                             // concat(L,R)
                #pragma unroll
                for (int kbl = 0; kbl < 4; kbl++) {
                    bf16x8 bfr[4];
                    #pragma unroll
                    for (int nt = 0; nt < 4; nt++)
                        bfr[nt] = *(const bf16x8*)(Bp + kbl * 2048 + q * 512 + (nt * 16 + sub) * 8);
                    #pragma unroll
                    for (int c = 0; c < 4; c++) {
                        if (!act[c]) continue;
                        int off = (kbl & 1) * 32 + ((kbl >> 1) ? XSTR : 0);
                        bf16x8 a = *(const bf16x8*)(Xs + slotL[c] + off + q * 8);
                        #pragma unroll
                        for (int nt = 0; nt < 4; nt++)
                            acc[c][nt] = __builtin_amdgcn_mfma_f32_16x16x32_bf16(a, bfr[nt], acc[c][nt], 0, 0, 0);
                    }
                }
            }
            __syncthreads();
            sg++;
        }

        // epilogue
        if (lidx < 4) {
            #pragma unroll
            for (int c = 0; c < 4; c++) {
                if (!act[c]) continue;
                #pragma unroll
                for (int nt = 0; nt < 4; nt++) {
                    int e = nt * 16 + sub;
                    #pragma unroll
                    for (int rr = 0; rr < 4; rr++) {
                        int m = (wave * chpw + c) * 16 + q * 4 + rr;
                        if (m < nodes) {
                            int t = m >> lg, n = m & (cnew - 1);
                            Xs[(t * 32 + n) * XSTR + e] = f2b(tanhf(scrub(acc[c][nt][rr] + biasC[e])));
                        }
                    }
                }
            }
            __syncthreads();
        } else {
            if (act[0]) {
                #pragma unroll
                for (int nt = 0; nt < 4; nt++) {
                    int e = nt * 16 + sub;
                    #pragma unroll
                    for (int rr = 0; rr < 4; rr++) {
                        int m = q * 4 + rr;      // tree index
                        if (m < 8)
                            g_roots[((size_t)wg * 8 + m) * 64 + e] =
                                f2b(tanhf(scrub(acc[0][nt][rr] + biasC[e])));
                    }
                }
            }
        }
    }
}

// ---------- kernel: final cpr/cprt + leaky_relu + softmax, W=2 ----------
__global__ __launch_bounds__(128, 1) void k_final(const void* __restrict__ voc_b,
                                                  void* __restrict__ out)
{
    __shared__ __attribute__((aligned(16))) unsigned short Lv[64 * XSTR], Rv[64 * XSTR];
    __shared__ __attribute__((aligned(16))) unsigned short Bs[2][STG];
    __shared__ float actS[64][65];
    __shared__ float smw[7][64];
    __shared__ float smbS[7];
    __shared__ float biasF[64];
    const int tid = threadIdx.x, wg = blockIdx.x;
    const int isb = detect_isb(voc_b);
    if (tid < 64) biasF[tid] = g_biasF[tid];
    if (tid < 7)  smbS[tid] = g_smb[tid];
    for (int z = tid; z < 448; z += 128) smw[z >> 6][z & 63] = g_smw[z];

    {   // stage roots: one row per thread
        int item = tid & 63; bool isR = tid >= 64;
        const uint4* src = (const uint4*)(g_roots + (size_t)((isR ? 1024 : 0) + wg * 64 + item) * 64);
        uint4* dst = (uint4*)((isR ? Rv : Lv) + item * XSTR);
        #pragma unroll
        for (int z = 0; z < 8; z++) dst[z] = src[z];
    }

    uint4 r[8];
    #pragma unroll
    for (int j = 0; j < 8; j++)
        r[j] = *(const uint4*)(g_cprtU + j * 1024 + (size_t)tid * 8);

    __syncthreads();

    const int lane = tid & 63, wave = tid >> 6;
    const int q = lane >> 4, sub = lane & 15;

    int rowLo[2];
    float Rf[2][2][8];                           // kron = l[i] * r[j]
    #pragma unroll
    for (int c = 0; c < 2; c++) {
        int item = (wave * 2 + c) * 16 + sub;    // 0..63
        rowLo[c] = item * XSTR;
        bf16x8 o0 = *(const bf16x8*)(Rv + rowLo[c] + q * 8);
        bf16x8 o1 = *(const bf16x8*)(Rv + rowLo[c] + 32 + q * 8);
        #pragma unroll
        for (int z = 0; z < 8; z++) { Rf[c][0][z] = (float)o0[z]; Rf[c][1][z] = (float)o1[z]; }
    }

    f32x4 acc[2][4];
    #pragma unroll
    for (int c = 0; c < 2; c++)
        #pragma unroll
        for (int nt = 0; nt < 4; nt++)
            #pragma unroll
            for (int z = 0; z < 4; z++) acc[c][nt][z] = 0.f;

    for (int s = 0; s < NSTAGE; s++) {
        const int par = s & 1;
        #pragma unroll
        for (int j = 0; j < 8; j++)
            *(uint4*)(Bs[par] + j * 1024 + tid * 8) = r[j];
        __syncthreads();
        if (s < NSTAGE - 1) {
            const unsigned short* base = g_cprtU + (size_t)(s + 1) * STG;
            #pragma unroll
            for (int j = 0; j < 8; j++)
                r[j] = *(const uint4*)(base + j * 1024 + (size_t)tid * 8);
        }
        const unsigned short* Bp = Bs[par];
        if (s < 32) {
            float Li[2][2];
            #pragma unroll
            for (int c = 0; c < 2; c++) {
                unsigned int lp = *(const unsigned int*)(Lv + rowLo[c] + 2 * s);
                Li[c][0] = b2f((unsigned short)(lp & 0xFFFFu));
                Li[c][1] = b2f((unsigned short)(lp >> 16));
            }
            #pragma unroll
            for (int ii = 0; ii < 2; ii++)
                #pragma unroll
                for (int p2 = 0; p2 < 2; p2++) {
                    int kbl = 2 * ii + p2;
                    bf16x8 bfr[4];
                    #pragma unroll
                    for (int nt = 0; nt < 4; nt++)
                        bfr[nt] = *(const bf16x8*)(Bp + kbl * 2048 + q * 512 + (nt * 16 + sub) * 8);
                    #pragma unroll
                    for (int c = 0; c < 2; c++) {
                        bf16x8 afr;
                        #pragma unroll
                        for (int z = 0; z < 8; z++) afr[z] = (__bf16)(Rf[c][p2][z] * Li[c][ii]);
                        #pragma unroll
                        for (int nt = 0; nt < 4; nt++)
                            acc[c][nt] = __builtin_amdgcn_mfma_f32_16x16x32_bf16(afr, bfr[nt], acc[c][nt], 0, 0, 0);
                    }
                }
        } else {                                 // concat(l, r)
            #pragma unroll
            for (int kbl = 0; kbl < 4; kbl++) {
                bf16x8 bfr[4];
                #pragma unroll
                for (int nt = 0; nt < 4; nt++)
                    bfr[nt] = *(const bf16x8*)(Bp + kbl * 2048 + q * 512 + (nt * 16 + sub) * 8);
                #pragma unroll
                for (int c = 0; c < 2; c++) {
                    const unsigned short* base = (kbl >> 1) ? Rv : Lv;
                    bf16x8 a = *(const bf16x8*)(base + rowLo[c] + (kbl & 1) * 32 + q * 8);
                    #pragma unroll
                    for (int nt = 0; nt < 4; nt++)
                        acc[c][nt] = __builtin_amdgcn_mfma_f32_16x16x32_bf16(a, bfr[nt], acc[c][nt], 0, 0, 0);
                }
            }
        }
        __syncthreads();
    }

    // epilogue: bias + leaky_relu -> LDS
    #pragma unroll
    for (int c = 0; c < 2; c++)
        #pragma unroll
        for (int nt = 0; nt < 4; nt++) {
            int e = nt * 16 + sub;
            #pragma unroll
            for (int rr = 0; rr < 4; rr++) {
                int it = (wave * 2 + c) * 16 + q * 4 + rr;
                float v = scrub(acc[c][nt][rr] + biasF[e]);
                v = (v > 0.f) ? v : 0.01f * v;
                actS[it][e] = v;
            }
        }
    __syncthreads();

    if (tid < 64) {
        float lg[7];
        #pragma unroll
        for (int j = 0; j < 7; j++) lg[j] = smbS[j];
        for (int e = 0; e < 64; e++) {
            float a = actS[tid][e];
            #pragma unroll
            for (int j = 0; j < 7; j++) lg[j] += smw[j][e] * a;
        }
        float mx = lg[0];
        #pragma unroll
        for (int j = 1; j < 7; j++) mx = fmaxf(mx, lg[j]);
        float s = 0.f, p[7];
        #pragma unroll
        for (int j = 0; j < 7; j++) { p[j] = expf(lg[j] - mx); s += p[j]; }
        float inv = 1.f / s;
        size_t b = (size_t)wg * 64 + tid;
        if (isb) {
            unsigned short* o = (unsigned short*)out;
            #pragma unroll
            for (int j = 0; j < 7; j++) o[b * 7 + j] = f2b(p[j] * inv);
        } else {
            float* o = (float*)out;
            #pragma unroll
            for (int j = 0; j < 7; j++) o[b * 7 + j] = p[j] * inv;
        }
    }
}

// ---------- host launcher ----------
extern "C" void kernel_launch(void* const* d_in, const int* in_sizes, int n_in,
                              void* d_out, int out_size, void* d_ws, size_t ws_size,
                              hipStream_t stream) {
    const int* lleaf = (const int*)d_in[0];
    const int* rleaf = (const int*)d_in[1];
    const void* voc_w  = d_in[2];
    const void* voc_b  = d_in[3];
    const void* cps_w  = d_in[4];
    const void* cps_b  = d_in[5];
    const void* cpst_w = d_in[6];
    const void* cpst_b = d_in[7];
    const void* cpr_w  = d_in[8];
    const void* cpr_b  = d_in[9];
    const void* cprt_w = d_in[10];
    const void* cprt_b = d_in[11];
    const void* sm_w   = d_in[12];
    const void* sm_b   = d_in[13];

    k_reorder<<<NSTAGE, 256, 0, stream>>>(voc_b, cps_w, cps_b, cpst_w, cpst_b,
                                          cpr_w, cpr_b, cprt_w, cprt_b, sm_w, sm_b);
    k_vocT<<<(VOC + 63) / 64, 256, 0, stream>>>(voc_w, voc_b);
    k_L0<<<256, 256, 0, stream>>>(lleaf, rleaf);
    k_tree<<<256, 128, 0, stream>>>();
    k_final<<<16, 128, 0, stream>>>(voc_b, (unsigned short*)d_out);
}

// Round 8
// 327.258 us; speedup vs baseline: 1.8107x; 1.8107x over previous
//
#include <hip/hip_runtime.h>
#include <hip/hip_bf16.h>
#include <cstdint>
#include <cstddef>

// ---------- types ----------
typedef __bf16 bf16x8 __attribute__((ext_vector_type(8)));
typedef float  f32x4  __attribute__((ext_vector_type(4)));

#define VOC    50000
#define W2     4224      // unified K: 4096 (kron) + 128 (concat)
#define NSTAGE 33        // 33 stages x 128 k
#define STG    8192      // elems per stage (128 k x 64 n) = 16 KB
#define XSTR   72        // LDS row stride in bf16 elems (144 B)

// ---------- static device scratch ----------
__device__ __attribute__((aligned(256))) unsigned short g_vocT[(size_t)VOC * 64];
__device__ __attribute__((aligned(256))) unsigned short g_X1[(size_t)65536 * 64];  // L0 outputs
__device__ __attribute__((aligned(256))) unsigned short g_roots[2048 * 64];
// weights in stage-fragment order: d = s*8192 + kbl*2048 + q*512 + n*8 + z
// = W[n][k], k = s*128 + kbl*32 + q*8 + z   (s=32 holds the concat weights)
__device__ __attribute__((aligned(256))) unsigned short g_cpstU[64 * W2];
__device__ __attribute__((aligned(256))) unsigned short g_cprtU[64 * W2];
__device__ float g_smw[7 * 64];
__device__ float g_smb[7];
__device__ float g_biasC[64];   // cps_b + cpst_b
__device__ float g_biasF[64];   // cpr_b + cprt_b

__device__ __forceinline__ float b2f(unsigned short u) {
    unsigned int x = ((unsigned int)u) << 16;
    return __builtin_bit_cast(float, x);
}
__device__ __forceinline__ unsigned short f2b(float f) {
    return __builtin_bit_cast(unsigned short, (__bf16)f);
}
__device__ __forceinline__ float scrub(float v) {
    return fminf(fmaxf(v, -64.f), 64.f);
}
__device__ __forceinline__ float ldf(const void* p, size_t i, int isb) {
    return isb ? b2f(((const unsigned short*)p)[i]) : ((const float*)p)[i];
}
__device__ __forceinline__ int detect_isb(const void* voc_b) {
    const unsigned int* p = (const unsigned int*)voc_b;
    int ok = 1;
    for (int k = 0; k < 32; k++) {
        float v = b2f((unsigned short)(p[k] & 0xFFFFu));
        if (!(fabsf(v) <= 0.0502f)) ok = 0;
    }
    return ok;
}

// ---------- kernel: reorder weights into stage-fragment order (coalesced) ----------
__global__ __launch_bounds__(256) void k_reorder(
    const void* voc_b,
    const void* cps_w, const void* cps_b, const void* cpst_w, const void* cpst_b,
    const void* cpr_w, const void* cpr_b, const void* cprt_w, const void* cprt_b,
    const void* sm_w, const void* sm_b)
{
    __shared__ unsigned short tileA[64][132];
    __shared__ unsigned short tileB[64][132];
    const int isb = detect_isb(voc_b);
    const int s = blockIdx.x;          // 0..32
    const int tid = threadIdx.x;
    for (int j = 0; j < 32; j++) {     // read W[n][s*128 + kk], coalesced along kk
        int lin = j * 256 + tid;
        int n = lin >> 7, kk = lin & 127;
        float v1 = (s < 32) ? ldf(cpst_w, (size_t)n * 4096 + s * 128 + kk, isb)
                            : ldf(cps_w,  (size_t)n * 128 + kk, isb);
        float v2 = (s < 32) ? ldf(cprt_w, (size_t)n * 4096 + s * 128 + kk, isb)
                            : ldf(cpr_w,  (size_t)n * 128 + kk, isb);
        tileA[n][kk] = f2b(v1);
        tileB[n][kk] = f2b(v2);
    }
    __syncthreads();
    for (int j = 0; j < 32; j++) {     // write fragment order, coalesced along d
        int lin = j * 256 + tid;
        int kbl = lin >> 11, rem = lin & 2047;
        int q = rem >> 9, rem2 = rem & 511;
        int n = rem2 >> 3, z = rem2 & 7;
        int kk = kbl * 32 + q * 8 + z;
        g_cpstU[(size_t)s * STG + lin] = tileA[n][kk];
        g_cprtU[(size_t)s * STG + lin] = tileB[n][kk];
    }
    if (s == 0) {
        for (int i = tid; i < 448; i += 256) g_smw[i] = ldf(sm_w, i, isb);
        if (tid < 64) {
            g_biasC[tid] = ldf(cps_b, tid, isb) + ldf(cpst_b, tid, isb);
            g_biasF[tid] = ldf(cpr_b, tid, isb) + ldf(cprt_b, tid, isb);
        }
        if (tid < 7) g_smb[tid] = ldf(sm_b, tid, isb);
    }
}

// ---------- kernel: voc_w (64 x 50000) -> g_vocT[50000][64] bf16, fold voc_b ----------
__global__ __launch_bounds__(256) void k_vocT(const void* __restrict__ voc_w,
                                              const void* __restrict__ voc_b) {
    __shared__ float tile[64][65];
    __shared__ float vb[64];
    const int isb = detect_isb(voc_b);
    int t = threadIdx.x;
    if (t < 64) vb[t] = ldf(voc_b, t, isb);
    int v0 = blockIdx.x * 64;
    int vl = t & 63, dr = t >> 6;
    #pragma unroll
    for (int i = 0; i < 16; i++) {
        int d = dr * 16 + i;
        int v = v0 + vl;
        tile[vl][d] = (v < VOC) ? ldf(voc_w, (size_t)d * VOC + v, isb) : 0.f;
    }
    __syncthreads();
    int dl = t & 63, vr0 = t >> 6;
    #pragma unroll
    for (int i = 0; i < 16; i++) {
        int vr = vr0 * 16 + i;
        int v = v0 + vr;
        if (v < VOC) g_vocT[(size_t)v * 64 + dl] = f2b(tile[vr][dl] + vb[dl]);
    }
}

// ---------- kernel: level 0 (leaves -> 32 nodes/tree), 8 trees/WG, 8 waves, N-split ----------
__global__ __launch_bounds__(512, 1) void k_L0(const int* __restrict__ lleaf,
                                               const int* __restrict__ rleaf)
{
    __shared__ __attribute__((aligned(16))) unsigned short Xs[512 * XSTR];  // 73728 B
    __shared__ __attribute__((aligned(16))) unsigned short Bs[2][STG];      // 32 KB
    __shared__ float biasC[64];
    const int tid = threadIdx.x;                 // 0..511
    const int wg  = blockIdx.x;                  // 0..255
    if (tid < 64) biasC[tid] = g_biasC[tid];

    // ---- leaf gather: one row per thread ----
    {
        int t = tid >> 6, i = tid & 63;
        int g = wg * 8 + t;                      // 0..1023 left, 1024..2047 right
        int b = (g < 1024) ? g : g - 1024;
        const int* lv = (g < 1024) ? lleaf : rleaf;
        int idx = lv[b * 64 + i];
        idx = (idx < 0) ? 0 : ((idx >= VOC) ? VOC - 1 : idx);
        const uint4* src = (const uint4*)(g_vocT + (size_t)idx * 64);
        uint4* dst = (uint4*)(Xs + tid * XSTR);
        #pragma unroll
        for (int z = 0; z < 8; z++) dst[z] = src[z];
    }

    // prefetch stage 0 (32 B/thread)
    uint4 r0 = *(const uint4*)(g_cpstU + (size_t)tid * 8);
    uint4 r1 = *(const uint4*)(g_cpstU + 4096 + (size_t)tid * 8);

    __syncthreads();

    const int lane = tid & 63, wave = tid >> 6;
    const int q = lane >> 4, sub = lane & 15;
    const int pair = wave & 3, h = wave >> 2;    // pair owns M-chunks; h owns nt-half

    int slotL[4];
    float Lf[4][2][8];
    #pragma unroll
    for (int c = 0; c < 4; c++) {
        int m = (pair * 4 + c) * 16 + sub;       // 0..255
        int t = m >> 5, n = m & 31;
        slotL[c] = (t * 64 + 2 * n) * XSTR;
        bf16x8 o0 = *(const bf16x8*)(Xs + slotL[c] + q * 8);
        bf16x8 o1 = *(const bf16x8*)(Xs + slotL[c] + 32 + q * 8);
        #pragma unroll
        for (int z = 0; z < 8; z++) { Lf[c][0][z] = (float)o0[z]; Lf[c][1][z] = (float)o1[z]; }
    }

    f32x4 acc[4][2];
    #pragma unroll
    for (int c = 0; c < 4; c++)
        #pragma unroll
        for (int ntl = 0; ntl < 2; ntl++)
            #pragma unroll
            for (int z = 0; z < 4; z++) acc[c][ntl][z] = 0.f;

    for (int s = 0; s < NSTAGE; s++) {
        const int par = s & 1;
        *(uint4*)(Bs[par] + tid * 8) = r0;
        *(uint4*)(Bs[par] + 4096 + tid * 8) = r1;
        __syncthreads();
        if (s < NSTAGE - 1) {
            const unsigned short* base = g_cpstU + (size_t)(s + 1) * STG;
            r0 = *(const uint4*)(base + tid * 8);
            r1 = *(const uint4*)(base + 4096 + (size_t)tid * 8);
        }
        const unsigned short* Bp = Bs[par];
        if (s < 32) {                            // kron
            float Li[4][2];
            #pragma unroll
            for (int c = 0; c < 4; c++) {
                unsigned int lp = *(const unsigned int*)(Xs + slotL[c] + 2 * s);
                Li[c][0] = b2f((unsigned short)(lp & 0xFFFFu));
                Li[c][1] = b2f((unsigned short)(lp >> 16));
            }
            #pragma unroll
            for (int ii = 0; ii < 2; ii++)
                #pragma unroll
                for (int p2 = 0; p2 < 2; p2++) {
                    int kbl = 2 * ii + p2;
                    bf16x8 bfr[2];
                    #pragma unroll
                    for (int ntl = 0; ntl < 2; ntl++) {
                        int nt = h * 2 + ntl;
                        bfr[ntl] = *(const bf16x8*)(Bp + kbl * 2048 + q * 512 + (nt * 16 + sub) * 8);
                    }
                    #pragma unroll
                    for (int c = 0; c < 4; c++) {
                        bf16x8 afr;
                        #pragma unroll
                        for (int z = 0; z < 8; z++) afr[z] = (__bf16)(Lf[c][p2][z] * Li[c][ii]);
                        #pragma unroll
                        for (int ntl = 0; ntl < 2; ntl++)
                            acc[c][ntl] = __builtin_amdgcn_mfma_f32_16x16x32_bf16(afr, bfr[ntl], acc[c][ntl], 0, 0, 0);
                    }
                }
        } else {                                 // concat(L,R)
            #pragma unroll
            for (int kbl = 0; kbl < 4; kbl++) {
                bf16x8 bfr[2];
                #pragma unroll
                for (int ntl = 0; ntl < 2; ntl++) {
                    int nt = h * 2 + ntl;
                    bfr[ntl] = *(const bf16x8*)(Bp + kbl * 2048 + q * 512 + (nt * 16 + sub) * 8);
                }
                #pragma unroll
                for (int c = 0; c < 4; c++) {
                    int off = (kbl & 1) * 32 + ((kbl >> 1) ? XSTR : 0);
                    bf16x8 a = *(const bf16x8*)(Xs + slotL[c] + off + q * 8);
                    #pragma unroll
                    for (int ntl = 0; ntl < 2; ntl++)
                        acc[c][ntl] = __builtin_amdgcn_mfma_f32_16x16x32_bf16(a, bfr[ntl], acc[c][ntl], 0, 0, 0);
                }
            }
        }
        __syncthreads();
    }

    // epilogue -> g_X1
    #pragma unroll
    for (int c = 0; c < 4; c++)
        #pragma unroll
        for (int ntl = 0; ntl < 2; ntl++) {
            int e = (h * 2 + ntl) * 16 + sub;
            #pragma unroll
            for (int rr = 0; rr < 4; rr++) {
                int m = (pair * 4 + c) * 16 + q * 4 + rr;
                g_X1[((size_t)wg * 256 + m) * 64 + e] = f2b(tanhf(scrub(acc[c][ntl][rr] + biasC[e])));
            }
        }
}

// ---------- kernel: levels 1..5 fused, 8 trees/WG (32-slot trees), 8 waves, N-split ----------
__global__ __launch_bounds__(512, 1) void k_tree()
{
    __shared__ __attribute__((aligned(16))) unsigned short Xs[256 * XSTR];  // 36864 B
    __shared__ __attribute__((aligned(16))) unsigned short Bs[2][STG];      // 32 KB
    __shared__ float biasC[64];
    const int tid = threadIdx.x;                 // 0..511
    const int wg  = blockIdx.x;                  // 0..255
    if (tid < 64) biasC[tid] = g_biasC[tid];

    // stage 256 L0-output rows (one half-row per thread)
    {
        int row = tid >> 1, half = tid & 1;
        const uint4* src = (const uint4*)(g_X1 + ((size_t)wg * 256 + row) * 64 + half * 32);
        uint4* dst = (uint4*)(Xs + row * XSTR + half * 32);
        #pragma unroll
        for (int z = 0; z < 4; z++) dst[z] = src[z];
    }

    uint4 r0 = *(const uint4*)(g_cpstU + (size_t)tid * 8);
    uint4 r1 = *(const uint4*)(g_cpstU + 4096 + (size_t)tid * 8);

    __syncthreads();

    const int lane = tid & 63, wave = tid >> 6;
    const int q = lane >> 4, sub = lane & 15;
    const int pair = wave & 3, h = wave >> 2;

    int sg = 0;
    for (int lidx = 0; lidx < 5; lidx++) {
        const int lg = 4 - lidx;                 // outputs/tree = 1<<lg
        const int cnew = 1 << lg;
        const int nodes = 8 << lg;               // 128,64,32,16,8
        const int nchunks = (nodes + 15) >> 4;   // 8,4,2,1,1
        const int cpp = (nchunks >= 4) ? (nchunks >> 2) : 1;   // chunks per pair: 2,1,1,1,1

        int act[2], slotL[2];
        float Lf[2][2][8];
        #pragma unroll
        for (int c = 0; c < 2; c++) {
            int ch = pair * cpp + c;
            act[c] = (c < cpp) && (ch < nchunks);
            int m = ch * 16 + sub;
            if (m >= nodes) m = 0;
            int t = m >> lg, n = m & (cnew - 1);
            slotL[c] = (t * 32 + 2 * n) * XSTR;
            if (act[c]) {
                bf16x8 o0 = *(const bf16x8*)(Xs + slotL[c] + q * 8);
                bf16x8 o1 = *(const bf16x8*)(Xs + slotL[c] + 32 + q * 8);
                #pragma unroll
                for (int z = 0; z < 8; z++) { Lf[c][0][z] = (float)o0[z]; Lf[c][1][z] = (float)o1[z]; }
            }
        }

        f32x4 acc[2][2];
        #pragma unroll
        for (int c = 0; c < 2; c++)
            #pragma unroll
            for (int ntl = 0; ntl < 2; ntl++)
                #pragma unroll
                for (int z = 0; z < 4; z++) acc[c][ntl][z] = 0.f;

        for (int s = 0; s < NSTAGE; s++) {
            const int par = sg & 1;
            *(uint4*)(Bs[par] + tid * 8) = r0;
            *(uint4*)(Bs[par] + 4096 + tid * 8) = r1;
            __syncthreads();
            {   // prefetch next stage (wraps at level boundary: same weights)
                int sn = (s == NSTAGE - 1) ? 0 : s + 1;
                const unsigned short* base = g_cpstU + (size_t)sn * STG;
                r0 = *(const uint4*)(base + tid * 8);
                r1 = *(const uint4*)(base + 4096 + (size_t)tid * 8);
            }
            const unsigned short* Bp = Bs[par];
            if (s < 32) {                        // kron
                float Li[2][2];
                #pragma unroll
                for (int c = 0; c < 2; c++) {
                    if (!act[c]) continue;
                    unsigned int lp = *(const unsigned int*)(Xs + slotL[c] + 2 * s);
                    Li[c][0] = b2f((unsigned short)(lp & 0xFFFFu));
                    Li[c][1] = b2f((unsigned short)(lp >> 16));
                }
                #pragma unroll
                for (int ii = 0; ii < 2; ii++)
                    #pragma unroll
                    for (int p2 = 0; p2 < 2; p2++) {
                        int kbl = 2 * ii + p2;
                        bf16x8 bfr[2];
                        #pragma unroll
                        for (int ntl = 0; ntl < 2; ntl++) {
                            int nt = h * 2 + ntl;
                            bfr[ntl] = *(const bf16x8*)(Bp + kbl * 2048 + q * 512 + (nt * 16 + sub) * 8);
                        }
                        #pragma unroll
                        for (int c = 0; c < 2; c++) {
                            if (!act[c]) continue;
                            bf16x8 afr;
                            #pragma unroll
                            for (int z = 0; z < 8; z++) afr[z] = (__bf16)(Lf[c][p2][z] * Li[c][ii]);
                            #pragma unroll
                            for (int ntl = 0; ntl < 2; ntl++)
                                acc[c][ntl] = __builtin_amdgcn_mfma_f32_16x16x32_bf16(afr, bfr[ntl], acc[c][ntl], 0, 0, 0);
                        }
                    }
            } else {                             // concat(L,R)
                #pragma unroll
                for (int kbl = 0; kbl < 4; kbl++) {
                    bf16x8 bfr[2];
                    #pragma unroll
                    for (int ntl = 0; ntl < 2; ntl++) {
                        int nt = h * 2 + ntl;
                        bfr[ntl] = *(const bf16x8*)(Bp + kbl * 2048 + q * 512 + (nt * 16 + sub) * 8);
                    }
                    #pragma unroll
                    for (int c = 0; c < 2; c++) {
                        if (!act[c]) continue;
                        int off = (kbl & 1) * 32 + ((kbl >> 1) ? XSTR : 0);
                        bf16x8 a = *(const bf16x8*)(Xs + slotL[c] + off + q * 8);
                        #pragma unroll
                        for (int ntl = 0; ntl < 2; ntl++)
                            acc[c][ntl] = __builtin_amdgcn_mfma_f32_16x16x32_bf16(a, bfr[ntl], acc[c][ntl], 0, 0, 0);
                    }
                }
            }
            __syncthreads();
            sg++;
        }

        // epilogue
        if (lidx < 4) {
            #pragma unroll
            for (int c = 0; c < 2; c++) {
                if (!act[c]) continue;
                #pragma unroll
                for (int ntl = 0; ntl < 2; ntl++) {
                    int e = (h * 2 + ntl) * 16 + sub;
                    #pragma unroll
                    for (int rr = 0; rr < 4; rr++) {
                        int m = (pair * cpp + c) * 16 + q * 4 + rr;
                        if (m < nodes) {
                            int t = m >> lg, n = m & (cnew - 1);
                            Xs[(t * 32 + n) * XSTR + e] = f2b(tanhf(scrub(acc[c][ntl][rr] + biasC[e])));
                        }
                    }
                }
            }
            __syncthreads();
        } else {
            if (act[0]) {
                #pragma unroll
                for (int ntl = 0; ntl < 2; ntl++) {
                    int e = (h * 2 + ntl) * 16 + sub;
                    #pragma unroll
                    for (int rr = 0; rr < 4; rr++) {
                        int m = q * 4 + rr;      // tree index
                        if (m < 8)
                            g_roots[((size_t)wg * 8 + m) * 64 + e] =
                                f2b(tanhf(scrub(acc[0][ntl][rr] + biasC[e])));
                    }
                }
            }
        }
    }
}

// ---------- kernel: final cpr/cprt + leaky_relu + softmax; 16 items/WG, nt per wave ----------
__global__ __launch_bounds__(256, 1) void k_final(const void* __restrict__ voc_b,
                                                  void* __restrict__ out)
{
    __shared__ __attribute__((aligned(16))) unsigned short Lv[16 * XSTR], Rv[16 * XSTR];
    __shared__ __attribute__((aligned(16))) unsigned short Bs[2][STG];
    __shared__ float actS[16][65];
    __shared__ float smw[7][64];
    __shared__ float smbS[7];
    __shared__ float biasF[64];
    const int tid = threadIdx.x, wg = blockIdx.x;   // 64 WGs
    const int isb = detect_isb(voc_b);
    if (tid < 64) biasF[tid] = g_biasF[tid];
    if (tid < 7)  smbS[tid] = g_smb[tid];
    for (int z = tid; z < 448; z += 256) smw[z >> 6][z & 63] = g_smw[z];

    if (tid < 128) {   // stage 16 l-roots + 16 r-roots (4 x uint4 per row)
        int tens = tid >> 6, row = (tid >> 2) & 15, part = tid & 3;
        const unsigned short* src = g_roots + (size_t)((tens ? 1024 : 0) + wg * 16 + row) * 64 + part * 16;
        unsigned short* dst = (tens ? Rv : Lv) + row * XSTR + part * 16;
        *(uint4*)dst = *(const uint4*)src;
        *(uint4*)(dst + 8) = *(const uint4*)(src + 8);
    }

    uint4 r[4];
    #pragma unroll
    for (int j = 0; j < 4; j++)
        r[j] = *(const uint4*)(g_cprtU + j * 2048 + (size_t)tid * 8);

    __syncthreads();

    const int lane = tid & 63, wave = tid >> 6;  // wave = nt
    const int q = lane >> 4, sub = lane & 15;
    const int rowLo = sub * XSTR;                // A-row = item = sub

    float Rf[2][8];                              // kron = l[i] * r[j]
    {
        bf16x8 o0 = *(const bf16x8*)(Rv + rowLo + q * 8);
        bf16x8 o1 = *(const bf16x8*)(Rv + rowLo + 32 + q * 8);
        #pragma unroll
        for (int z = 0; z < 8; z++) { Rf[0][z] = (float)o0[z]; Rf[1][z] = (float)o1[z]; }
    }

    f32x4 acc;
    #pragma unroll
    for (int z = 0; z < 4; z++) acc[z] = 0.f;

    for (int s = 0; s < NSTAGE; s++) {
        const int par = s & 1;
        #pragma unroll
        for (int j = 0; j < 4; j++)
            *(uint4*)(Bs[par] + j * 2048 + tid * 8) = r[j];
        __syncthreads();
        if (s < NSTAGE - 1) {
            const unsigned short* base = g_cprtU + (size_t)(s + 1) * STG;
            #pragma unroll
            for (int j = 0; j < 4; j++)
                r[j] = *(const uint4*)(base + j * 2048 + (size_t)tid * 8);
        }
        const unsigned short* Bp = Bs[par];
        if (s < 32) {
            unsigned int lp = *(const unsigned int*)(Lv + rowLo + 2 * s);
            float Li0 = b2f((unsigned short)(lp & 0xFFFFu));
            float Li1 = b2f((unsigned short)(lp >> 16));
            #pragma unroll
            for (int ii = 0; ii < 2; ii++)
                #pragma unroll
                for (int p2 = 0; p2 < 2; p2++) {
                    int kbl = 2 * ii + p2;
                    bf16x8 bfr = *(const bf16x8*)(Bp + kbl * 2048 + q * 512 + (wave * 16 + sub) * 8);
                    bf16x8 afr;
                    float Li = ii ? Li1 : Li0;
                    #pragma unroll
                    for (int z = 0; z < 8; z++) afr[z] = (__bf16)(Rf[p2][z] * Li);
                    acc = __builtin_amdgcn_mfma_f32_16x16x32_bf16(afr, bfr, acc, 0, 0, 0);
                }
        } else {                                 // concat(l, r)
            #pragma unroll
            for (int kbl = 0; kbl < 4; kbl++) {
                bf16x8 bfr = *(const bf16x8*)(Bp + kbl * 2048 + q * 512 + (wave * 16 + sub) * 8);
                const unsigned short* base = (kbl >> 1) ? Rv : Lv;
                bf16x8 a = *(const bf16x8*)(base + rowLo + (kbl & 1) * 32 + q * 8);
                acc = __builtin_amdgcn_mfma_f32_16x16x32_bf16(a, bfr, acc, 0, 0, 0);
            }
        }
        __syncthreads();
    }

    // epilogue: bias + leaky_relu -> LDS
    {
        int e = wave * 16 + sub;
        #pragma unroll
        for (int rr = 0; rr < 4; rr++) {
            int it = q * 4 + rr;
            float v = scrub(acc[rr] + biasF[e]);
            v = (v > 0.f) ? v : 0.01f * v;
            actS[it][e] = v;
        }
    }
    __syncthreads();

    if (tid < 16) {
        float lg[7];
        #pragma unroll
        for (int j = 0; j < 7; j++) lg[j] = smbS[j];
        for (int e = 0; e < 64; e++) {
            float a = actS[tid][e];
            #pragma unroll
            for (int j = 0; j < 7; j++) lg[j] += smw[j][e] * a;
        }
        float mx = lg[0];
        #pragma unroll
        for (int j = 1; j < 7; j++) mx = fmaxf(mx, lg[j]);
        float s = 0.f, p[7];
        #pragma unroll
        for (int j = 0; j < 7; j++) { p[j] = expf(lg[j] - mx); s += p[j]; }
        float inv = 1.f / s;
        size_t b = (size_t)wg * 16 + tid;
        if (isb) {
            unsigned short* o = (unsigned short*)out;
            #pragma unroll
            for (int j = 0; j < 7; j++) o[b * 7 + j] = f2b(p[j] * inv);
        } else {
            float* o = (float*)out;
            #pragma unroll
            for (int j = 0; j < 7; j++) o[b * 7 + j] = p[j] * inv;
        }
    }
}

// ---------- host launcher ----------
extern "C" void kernel_launch(void* const* d_in, const int* in_sizes, int n_in,
                              void* d_out, int out_size, void* d_ws, size_t ws_size,
                              hipStream_t stream) {
    const int* lleaf = (const int*)d_in[0];
    const int* rleaf = (const int*)d_in[1];
    const void* voc_w  = d_in[2];
    const void* voc_b  = d_in[3];
    const void* cps_w  = d_in[4];
    const void* cps_b  = d_in[5];
    const void* cpst_w = d_in[6];
    const void* cpst_b = d_in[7];
    const void* cpr_w  = d_in[8];
    const void* cpr_b  = d_in[9];
    const void* cprt_w = d_in[10];
    const void* cprt_b = d_in[11];
    const void* sm_w   = d_in[12];
    const void* sm_b   = d_in[13];

    k_reorder<<<NSTAGE, 256, 0, stream>>>(voc_b, cps_w, cps_b, cpst_w, cpst_b,
                                          cpr_w, cpr_b, cprt_w, cprt_b, sm_w, sm_b);
    k_vocT<<<(VOC + 63) / 64, 256, 0, stream>>>(voc_w, voc_b);
    k_L0<<<256, 512, 0, stream>>>(lleaf, rleaf);
    k_tree<<<256, 512, 0, stream>>>();
    k_final<<<64, 256, 0, stream>>>(voc_b, (unsigned short*)d_out);
}